// Round 12
// baseline (362.637 us; speedup 1.0000x reference)
//
#include <hip/hip_runtime.h>
#include <math.h>

#define NN 50000
#define EE 800000
#define NAPP 8             // A-applications; rho rel-err ~ 0.29^7 ~ 2e-4, output delta << threshold
#define NSLOT 8            // norm^2 partial slots per iteration, 1 cacheline apart

// ---- workspace byte offsets ----
static constexpr size_t O_CNT  = 0;         // N int32
static constexpr size_t O_RP   = 200192;    // (N+1) int32
static constexpr size_t O_FILL = 400640;    // N int32
static constexpr size_t O_EPK  = 600832;    // E * 8B packed {f32 val, i32 col} -> ends at 7000832
static constexpr size_t O_U0   = 7000832;   // N f32 (aliased: bsum/boff during CSR build)
static constexpr size_t O_U1   = 7201024;   // N f32
static constexpr size_t O_N2   = 7401216;   // NAPP * NSLOT*32 f32 (slot j at +j*128B)
static constexpr size_t O_WP   = 7414016;   // 128*128 f32 (projected W)
static constexpr size_t O_Y    = 7479552;   // N*128 bf16 (X@Wp + U@B), 12.8 MB

#define FMA4(ac, s, b) { ac.x = fmaf((s),(b).x,ac.x); ac.y = fmaf((s),(b).y,ac.y); \
                         ac.z = fmaf((s),(b).z,ac.z); ac.w = fmaf((s),(b).w,ac.w); }

__device__ __forceinline__ float slot_sum(const float* base){
  float s = 0.f;
  #pragma unroll
  for (int j = 0; j < NSLOT; ++j) s += base[j*32];
  return s;
}

__device__ __forceinline__ unsigned short f2bf(float x){   // RNE f32 -> bf16
  unsigned u = __float_as_uint(x);
  u = (u + 0x7FFFu + ((u >> 16) & 1u)) >> 16;
  return (unsigned short)u;
}

__global__ __launch_bounds__(256) void k_init(int* __restrict__ cnt, float* __restrict__ n2){
  int i = blockIdx.x*256 + threadIdx.x;
  if (i < NN) cnt[i] = 0;
  if (i < NAPP*NSLOT*32) n2[i] = 0.f;
}

__global__ __launch_bounds__(256) void k_hist(const int* __restrict__ erow, int* __restrict__ cnt){
  int e = blockIdx.x*256 + threadIdx.x;
  if (e < EE) atomicAdd(&cnt[erow[e]], 1);
}

// ---- hierarchical exclusive scan of cnt[] -> rp[], fill[] ----
__global__ __launch_bounds__(256) void k_bsum(const int* __restrict__ cnt, int* __restrict__ bsum){
  int i = blockIdx.x*256 + threadIdx.x;
  int v = (i < NN) ? cnt[i] : 0;
  for (int o=32;o>0;o>>=1) v += __shfl_down(v, o);
  __shared__ int red[4];
  int lane = threadIdx.x & 63, wv = threadIdx.x >> 6;
  if (lane == 0) red[wv] = v;
  __syncthreads();
  if (threadIdx.x == 0) bsum[blockIdx.x] = red[0]+red[1]+red[2]+red[3];
}

__global__ __launch_bounds__(256) void k_bscan(const int* __restrict__ bsum, int* __restrict__ boff){
  __shared__ int sd[256];
  int t = threadIdx.x;
  int v = (t < 196) ? bsum[t] : 0;
  sd[t] = v;
  __syncthreads();
  for (int off=1; off<256; off<<=1){
    int add = (t>=off) ? sd[t-off] : 0;
    __syncthreads();
    sd[t] += add;
    __syncthreads();
  }
  if (t < 196) boff[t] = sd[t] - v;   // exclusive block offset
}

__global__ __launch_bounds__(256) void k_scan3(const int* __restrict__ cnt, const int* __restrict__ boff,
                                               int* __restrict__ rp, int* __restrict__ fill){
  __shared__ int sd[256];
  int t = threadIdx.x, i = blockIdx.x*256 + t;
  int c = (i < NN) ? cnt[i] : 0;
  sd[t] = c;
  __syncthreads();
  for (int off=1; off<256; off<<=1){
    int add = (t>=off) ? sd[t-off] : 0;
    __syncthreads();
    sd[t] += add;
    __syncthreads();
  }
  int excl = sd[t] - c + boff[blockIdx.x];
  if (i < NN){ fill[i] = excl; rp[i+1] = excl + c; }
  if (i == 0) rp[0] = 0;
}

__global__ __launch_bounds__(256) void k_scatter(const int* __restrict__ erow, const int* __restrict__ ecol,
                                                 const float* __restrict__ ev, int* __restrict__ fill,
                                                 float2* __restrict__ epk){
  int e = blockIdx.x*256 + threadIdx.x;
  if (e < EE){
    int r = erow[e];
    int p = atomicAdd(&fill[r], 1);
    epk[p] = make_float2(ev[e], __int_as_float(ecol[e]));
  }
}

// One power-iteration step, 4 lanes per row. Scale for this step comes from the
// PREVIOUS launch's n2 slots (kernel boundary = grid barrier). Partials for this
// step go to 8 cacheline-spread slots — no same-line contention, no finalize.
__global__ __launch_bounds__(256) void k_spmv(const int* __restrict__ rp, const float2* __restrict__ epk,
                                              const float* __restrict__ uin, float* __restrict__ uout,
                                              const float* __restrict__ n2prev, float* __restrict__ n2cur,
                                              int first_flag){
  int tid = blockIdx.x*256 + threadIdx.x;
  int r = tid >> 2, q = tid & 3;
  float s = first_flag ? 0.004472135955f                      // 1/sqrt(50000): v0 = ones/sqrt(N)
                       : 1.0f / (sqrtf(slot_sum(n2prev)) + 1e-12f);
  float acc = 0.f;
  if (r < NN){
    int e0 = rp[r], e1 = rp[r+1];
    if (first_flag){
      for (int e = e0 + q; e < e1; e += 4) acc += epk[e].x;   // uin == all-ones (folded)
    } else {
      for (int e = e0 + q; e < e1; e += 4){
        float2 ed = epk[e];
        acc = fmaf(ed.x, uin[__float_as_int(ed.y)], acc);
      }
    }
  }
  acc += __shfl_xor(acc, 1);
  acc += __shfl_xor(acc, 2);
  acc *= s;
  float p2 = 0.f;
  if (r < NN && q == 0){ uout[r] = acc; p2 = acc*acc; }
  for (int o=32;o>0;o>>=1) p2 += __shfl_down(p2, o);
  __shared__ float red[4];
  int lane = threadIdx.x & 63, wv = threadIdx.x >> 6;
  if (lane == 0) red[wv] = p2;
  __syncthreads();
  if (threadIdx.x == 0)
    atomicAdd(&n2cur[(blockIdx.x & (NSLOT-1)) * 32], red[0]+red[1]+red[2]+red[3]);
}

// Row-wise L1-ball projection of W (one 128-thread block per row); v from last n2 slots
__global__ __launch_bounds__(128) void k_proj(const float* __restrict__ W, const float* __restrict__ n2last,
                                              float* __restrict__ Wp){
  __shared__ float sa[128];
  __shared__ float cs[128];
  __shared__ int wcnt[2];
  int row = blockIdx.x, j = threadIdx.x;
  float w  = W[row*128 + j];
  float aw = fabsf(w);
  float v  = 0.99f / (sqrtf(slot_sum(n2last)) + 1e-5f);       // kappa/(rho+eps)
  sa[j] = aw;
  __syncthreads();
  // bitonic sort ascending
  for (int k=2; k<=128; k<<=1){
    for (int jj=k>>1; jj>0; jj>>=1){
      int ix = j ^ jj;
      if (ix > j){
        float x = sa[j], y = sa[ix];
        bool up = ((j & k) == 0);
        if ((x > y) == up){ sa[j] = y; sa[ix] = x; }
      }
      __syncthreads();
    }
  }
  float d = sa[127 - j];                  // descending view
  cs[j] = d;
  __syncthreads();
  for (int off=1; off<128; off<<=1){      // inclusive scan
    float add = (j>=off) ? cs[j-off] : 0.f;
    __syncthreads();
    cs[j] += add;
    __syncthreads();
  }
  float l1 = cs[127];
  int flag = (d * (float)(j+1) > cs[j] - v) ? 1 : 0;
  unsigned long long bal = __ballot(flag);
  if ((j & 63) == 0) wcnt[j>>6] = __popcll(bal);
  __syncthreads();
  int rho = wcnt[0] + wcnt[1];            // >=1 always (v>0)
  float theta = (cs[rho-1] - v) / (float)rho;
  float wpv = copysignf(fmaxf(aw - theta, 0.f), w);
  Wp[row*128 + j] = (l1 > v) ? wpv : w;
}

// Y = X @ Wp + U @ B  (concatenated K=256), 64 rows x 128 cols per block, 8x4 per thread,
// register-prefetch pipeline (load chunk ci+1 to regs while computing chunk ci from LDS).
// As stride 36 floats (144 B): staging float4 writes balance all 32 banks (round-7-proven
// pattern, 0 conflicts measured); inner-loop A reads are 2-address broadcasts.
__global__ __launch_bounds__(256) void k_gemm(const float* __restrict__ X, const float* __restrict__ U,
                                              const float* __restrict__ Wp, const float* __restrict__ Bm,
                                              unsigned short* __restrict__ Ybf){
  __shared__ float As[64][36];            // [row][k]
  __shared__ float Ws[32][128];           // [k][col]
  int t  = threadIdx.x;
  int tc = t & 31, tr = t >> 5;           // tc: 4-col group (col=tc*4), tr: 8-row group (row=tr*8)
  int row0 = blockIdx.x * 64;
  int sr = t >> 3, skb = (t & 7) * 4;     // A staging: rows sr, sr+32; k-offset skb
  int gr0 = row0 + sr, gr1 = gr0 + 32;
  float4 pa0, pa1, pw[4];
  float4 acc[8];
  #pragma unroll
  for (int m=0;m<8;++m) acc[m] = make_float4(0.f,0.f,0.f,0.f);

  // prologue: load chunk 0 (X / Wp, ko=0) into regs
  pa0 = make_float4(0.f,0.f,0.f,0.f); pa1 = pa0;
  if (gr0 < NN) pa0 = *(const float4*)(X + (size_t)gr0*128 + skb);
  if (gr1 < NN) pa1 = *(const float4*)(X + (size_t)gr1*128 + skb);
  #pragma unroll
  for (int i=0;i<4;++i)
    pw[i] = *(const float4*)(Wp + (size_t)(tr + 8*i)*128 + tc*4);

  #pragma unroll 1
  for (int ci=0; ci<8; ++ci){
    // commit current chunk regs -> LDS
    *(float4*)&As[sr][skb]    = pa0;
    *(float4*)&As[sr+32][skb] = pa1;
    #pragma unroll
    for (int i=0;i<4;++i) *(float4*)&Ws[tr + 8*i][tc*4] = pw[i];
    __syncthreads();
    // prefetch next chunk into regs (latency hides under compute below)
    if (ci < 7){
      int cj = ci + 1;
      const float* asrc = (cj < 4) ? X  : U;
      const float* wsrc = (cj < 4) ? Wp : Bm;
      int ko = (cj & 3) * 32;
      pa0 = make_float4(0.f,0.f,0.f,0.f); pa1 = pa0;
      if (gr0 < NN) pa0 = *(const float4*)(asrc + (size_t)gr0*128 + ko + skb);
      if (gr1 < NN) pa1 = *(const float4*)(asrc + (size_t)gr1*128 + ko + skb);
      #pragma unroll
      for (int i=0;i<4;++i)
        pw[i] = *(const float4*)(wsrc + (size_t)(ko + tr + 8*i)*128 + tc*4);
    }
    // compute current chunk from LDS: 8 rows x 4 cols per thread
    #pragma unroll
    for (int k4=0;k4<8;++k4){
      float4 b0 = *(float4*)&Ws[k4*4+0][tc*4];
      float4 b1 = *(float4*)&Ws[k4*4+1][tc*4];
      float4 b2 = *(float4*)&Ws[k4*4+2][tc*4];
      float4 b3 = *(float4*)&Ws[k4*4+3][tc*4];
      #pragma unroll
      for (int m=0;m<8;++m){
        float4 a = *(float4*)&As[tr*8+m][k4*4];
        FMA4(acc[m], a.x, b0); FMA4(acc[m], a.y, b1);
        FMA4(acc[m], a.z, b2); FMA4(acc[m], a.w, b3);
      }
    }
    __syncthreads();
  }
  #pragma unroll
  for (int m=0;m<8;++m){
    int gr = row0 + tr*8 + m;
    if (gr < NN){
      ushort4 o;
      o.x = f2bf(acc[m].x); o.y = f2bf(acc[m].y); o.z = f2bf(acc[m].z); o.w = f2bf(acc[m].w);
      *(ushort4*)(Ybf + (size_t)gr*128 + tc*4) = o;
    }
  }
}

// out = relu(A @ Y_bf16), one wave per row; lane handles cols {2l, 2l+1} via one 4B gather/edge
__global__ __launch_bounds__(256) void k_spmm_relu(const int* __restrict__ rp, const float2* __restrict__ epk,
                                                   const unsigned int* __restrict__ Ybf2,  // N x 64 ushort2-words
                                                   float* __restrict__ out){
  int wv = threadIdx.x >> 6, lane = threadIdx.x & 63;
  int r = blockIdx.x*4 + wv;
  if (r >= NN) return;
  int e0 = rp[r], e1 = rp[r+1];
  float a0 = 0.f, a1 = 0.f;
  int e = e0;
  for (; e+2 <= e1; e += 2){
    float2 d0 = epk[e], d1 = epk[e+1];
    unsigned p0 = Ybf2[(size_t)__float_as_int(d0.y)*64 + lane];
    unsigned p1 = Ybf2[(size_t)__float_as_int(d1.y)*64 + lane];
    a0 = fmaf(d0.x, __uint_as_float(p0 << 16),         a0);
    a1 = fmaf(d0.x, __uint_as_float(p0 & 0xFFFF0000u), a1);
    a0 = fmaf(d1.x, __uint_as_float(p1 << 16),         a0);
    a1 = fmaf(d1.x, __uint_as_float(p1 & 0xFFFF0000u), a1);
  }
  if (e < e1){
    float2 d0 = epk[e];
    unsigned p0 = Ybf2[(size_t)__float_as_int(d0.y)*64 + lane];
    a0 = fmaf(d0.x, __uint_as_float(p0 << 16),         a0);
    a1 = fmaf(d0.x, __uint_as_float(p0 & 0xFFFF0000u), a1);
  }
  float2 o; o.x = fmaxf(a0, 0.f); o.y = fmaxf(a1, 0.f);
  *(float2*)(out + (size_t)r*128 + 2*lane) = o;
}

extern "C" void kernel_launch(void* const* d_in, const int* in_sizes, int n_in,
                              void* d_out, int out_size, void* d_ws, size_t ws_size,
                              hipStream_t stream) {
  const float* X  = (const float*)d_in[0];
  const float* U  = (const float*)d_in[1];
  const float* W  = (const float*)d_in[2];
  const float* Bm = (const float*)d_in[3];
  const float* ev = (const float*)d_in[4];
  const int*   ei = (const int*)d_in[5];
  const int* erow = ei;
  const int* ecol = ei + EE;

  char* ws = (char*)d_ws;
  int*            cnt  = (int*)           (ws + O_CNT);
  int*            rp   = (int*)           (ws + O_RP);
  int*            fill = (int*)           (ws + O_FILL);
  float2*         epk  = (float2*)        (ws + O_EPK);
  float*          ua   = (float*)         (ws + O_U0);
  float*          ub   = (float*)         (ws + O_U1);
  float*          n2   = (float*)         (ws + O_N2);
  float*          Wp   = (float*)         (ws + O_WP);
  unsigned short* Ybf  = (unsigned short*)(ws + O_Y);
  float*          out  = (float*)         d_out;
  // bsum/boff alias u0: used only during CSR build, before ua is first written (it=1)
  int*            bsum = (int*)           (ws + O_U0);
  int*            boff = (int*)           (ws + O_U0 + 1024);

  k_init   <<<196, 256, 0, stream>>>(cnt, n2);
  k_hist   <<<EE/256, 256, 0, stream>>>(erow, cnt);
  k_bsum   <<<196, 256, 0, stream>>>(cnt, bsum);
  k_bscan  <<<1, 256, 0, stream>>>(bsum, boff);
  k_scan3  <<<196, 256, 0, stream>>>(cnt, boff, rp, fill);
  k_scatter<<<EE/256, 256, 0, stream>>>(erow, ecol, ev, fill, epk);

  float* uav = ua; float* ubv = ub;
  for (int it = 0; it < NAPP; ++it){
    const float* n2prev = n2 + (it > 0 ? (it-1) : 0) * NSLOT*32;
    float*       n2cur  = n2 + it * NSLOT*32;
    k_spmv<<<782, 256, 0, stream>>>(rp, epk, uav, ubv, n2prev, n2cur, it == 0 ? 1 : 0);
    float* tmp = uav; uav = ubv; ubv = tmp;
  }

  k_proj     <<<128,   128, 0, stream>>>(W, n2 + (NAPP-1)*NSLOT*32, Wp);
  k_gemm     <<<782,   256, 0, stream>>>(X, U, Wp, Bm, Ybf);
  k_spmm_relu<<<12500, 256, 0, stream>>>(rp, epk, (const unsigned int*)Ybf, out);
}

// Round 13
// 351.262 us; speedup vs baseline: 1.0324x; 1.0324x over previous
//
#include <hip/hip_runtime.h>
#include <math.h>

#define NN 50000
#define EE 800000
#define NAPP 8             // A-applications; rho rel-err ~ 0.29^7 ~ 2e-4, output delta << threshold
#define NSLOT 8            // norm^2 partial slots per iteration, 1 cacheline apart

// ---- workspace byte offsets ----
static constexpr size_t O_CNT  = 0;         // N int32
static constexpr size_t O_RP   = 200192;    // (N+1) int32
static constexpr size_t O_FILL = 400640;    // N int32
static constexpr size_t O_EPK  = 600832;    // E * 8B packed {f32 val, i32 col} -> ends at 7000832
static constexpr size_t O_U0   = 7000832;   // N f32 (aliased: bsum/boff during CSR build)
static constexpr size_t O_U1   = 7201024;   // N f32
static constexpr size_t O_N2   = 7401216;   // NAPP * NSLOT*32 f32 (slot j at +j*128B)
static constexpr size_t O_WP   = 7414016;   // 128*128 f32 (projected W)
static constexpr size_t O_Y    = 7479552;   // N*128 bf16 (X@Wp + U@B), 12.8 MB

#define FMA4(ac, s, b) { ac.x = fmaf((s),(b).x,ac.x); ac.y = fmaf((s),(b).y,ac.y); \
                         ac.z = fmaf((s),(b).z,ac.z); ac.w = fmaf((s),(b).w,ac.w); }

typedef const __attribute__((address_space(1))) unsigned int* gas_u32p;
typedef __attribute__((address_space(3))) unsigned int* las_u32p;
__device__ __forceinline__ void gll16(const void* g, void* l){
  // async global->LDS DMA, 16B per lane; LDS dest = wave-uniform base + lane*16
  __builtin_amdgcn_global_load_lds((gas_u32p)g, (las_u32p)l, 16, 0, 0);
}

__device__ __forceinline__ float slot_sum(const float* base){
  float s = 0.f;
  #pragma unroll
  for (int j = 0; j < NSLOT; ++j) s += base[j*32];
  return s;
}

__device__ __forceinline__ unsigned short f2bf(float x){   // RNE f32 -> bf16
  unsigned u = __float_as_uint(x);
  u = (u + 0x7FFFu + ((u >> 16) & 1u)) >> 16;
  return (unsigned short)u;
}

__global__ __launch_bounds__(256) void k_init(int* __restrict__ cnt, float* __restrict__ n2){
  int i = blockIdx.x*256 + threadIdx.x;
  if (i < NN) cnt[i] = 0;
  if (i < NAPP*NSLOT*32) n2[i] = 0.f;
}

__global__ __launch_bounds__(256) void k_hist(const int* __restrict__ erow, int* __restrict__ cnt){
  int e = blockIdx.x*256 + threadIdx.x;
  if (e < EE) atomicAdd(&cnt[erow[e]], 1);
}

// ---- hierarchical exclusive scan of cnt[] -> rp[], fill[] ----
__global__ __launch_bounds__(256) void k_bsum(const int* __restrict__ cnt, int* __restrict__ bsum){
  int i = blockIdx.x*256 + threadIdx.x;
  int v = (i < NN) ? cnt[i] : 0;
  for (int o=32;o>0;o>>=1) v += __shfl_down(v, o);
  __shared__ int red[4];
  int lane = threadIdx.x & 63, wv = threadIdx.x >> 6;
  if (lane == 0) red[wv] = v;
  __syncthreads();
  if (threadIdx.x == 0) bsum[blockIdx.x] = red[0]+red[1]+red[2]+red[3];
}

__global__ __launch_bounds__(256) void k_bscan(const int* __restrict__ bsum, int* __restrict__ boff){
  __shared__ int sd[256];
  int t = threadIdx.x;
  int v = (t < 196) ? bsum[t] : 0;
  sd[t] = v;
  __syncthreads();
  for (int off=1; off<256; off<<=1){
    int add = (t>=off) ? sd[t-off] : 0;
    __syncthreads();
    sd[t] += add;
    __syncthreads();
  }
  if (t < 196) boff[t] = sd[t] - v;   // exclusive block offset
}

__global__ __launch_bounds__(256) void k_scan3(const int* __restrict__ cnt, const int* __restrict__ boff,
                                               int* __restrict__ rp, int* __restrict__ fill){
  __shared__ int sd[256];
  int t = threadIdx.x, i = blockIdx.x*256 + t;
  int c = (i < NN) ? cnt[i] : 0;
  sd[t] = c;
  __syncthreads();
  for (int off=1; off<256; off<<=1){
    int add = (t>=off) ? sd[t-off] : 0;
    __syncthreads();
    sd[t] += add;
    __syncthreads();
  }
  int excl = sd[t] - c + boff[blockIdx.x];
  if (i < NN){ fill[i] = excl; rp[i+1] = excl + c; }
  if (i == 0) rp[0] = 0;
}

__global__ __launch_bounds__(256) void k_scatter(const int* __restrict__ erow, const int* __restrict__ ecol,
                                                 const float* __restrict__ ev, int* __restrict__ fill,
                                                 float2* __restrict__ epk){
  int e = blockIdx.x*256 + threadIdx.x;
  if (e < EE){
    int r = erow[e];
    int p = atomicAdd(&fill[r], 1);
    epk[p] = make_float2(ev[e], __int_as_float(ecol[e]));
  }
}

// One power-iteration step, 4 lanes per row. Scale for this step comes from the
// PREVIOUS launch's n2 slots (kernel boundary = grid barrier). Partials for this
// step go to 8 cacheline-spread slots — no same-line contention, no finalize.
__global__ __launch_bounds__(256) void k_spmv(const int* __restrict__ rp, const float2* __restrict__ epk,
                                              const float* __restrict__ uin, float* __restrict__ uout,
                                              const float* __restrict__ n2prev, float* __restrict__ n2cur,
                                              int first_flag){
  int tid = blockIdx.x*256 + threadIdx.x;
  int r = tid >> 2, q = tid & 3;
  float s = first_flag ? 0.004472135955f                      // 1/sqrt(50000): v0 = ones/sqrt(N)
                       : 1.0f / (sqrtf(slot_sum(n2prev)) + 1e-12f);
  float acc = 0.f;
  if (r < NN){
    int e0 = rp[r], e1 = rp[r+1];
    if (first_flag){
      for (int e = e0 + q; e < e1; e += 4) acc += epk[e].x;   // uin == all-ones (folded)
    } else {
      for (int e = e0 + q; e < e1; e += 4){
        float2 ed = epk[e];
        acc = fmaf(ed.x, uin[__float_as_int(ed.y)], acc);
      }
    }
  }
  acc += __shfl_xor(acc, 1);
  acc += __shfl_xor(acc, 2);
  acc *= s;
  float p2 = 0.f;
  if (r < NN && q == 0){ uout[r] = acc; p2 = acc*acc; }
  for (int o=32;o>0;o>>=1) p2 += __shfl_down(p2, o);
  __shared__ float red[4];
  int lane = threadIdx.x & 63, wv = threadIdx.x >> 6;
  if (lane == 0) red[wv] = p2;
  __syncthreads();
  if (threadIdx.x == 0)
    atomicAdd(&n2cur[(blockIdx.x & (NSLOT-1)) * 32], red[0]+red[1]+red[2]+red[3]);
}

// Row-wise L1-ball projection of W (one 128-thread block per row); v from last n2 slots
__global__ __launch_bounds__(128) void k_proj(const float* __restrict__ W, const float* __restrict__ n2last,
                                              float* __restrict__ Wp){
  __shared__ float sa[128];
  __shared__ float cs[128];
  __shared__ int wcnt[2];
  int row = blockIdx.x, j = threadIdx.x;
  float w  = W[row*128 + j];
  float aw = fabsf(w);
  float v  = 0.99f / (sqrtf(slot_sum(n2last)) + 1e-5f);       // kappa/(rho+eps)
  sa[j] = aw;
  __syncthreads();
  // bitonic sort ascending
  for (int k=2; k<=128; k<<=1){
    for (int jj=k>>1; jj>0; jj>>=1){
      int ix = j ^ jj;
      if (ix > j){
        float x = sa[j], y = sa[ix];
        bool up = ((j & k) == 0);
        if ((x > y) == up){ sa[j] = y; sa[ix] = x; }
      }
      __syncthreads();
    }
  }
  float d = sa[127 - j];                  // descending view
  cs[j] = d;
  __syncthreads();
  for (int off=1; off<128; off<<=1){      // inclusive scan
    float add = (j>=off) ? cs[j-off] : 0.f;
    __syncthreads();
    cs[j] += add;
    __syncthreads();
  }
  float l1 = cs[127];
  int flag = (d * (float)(j+1) > cs[j] - v) ? 1 : 0;
  unsigned long long bal = __ballot(flag);
  if ((j & 63) == 0) wcnt[j>>6] = __popcll(bal);
  __syncthreads();
  int rho = wcnt[0] + wcnt[1];            // >=1 always (v>0)
  float theta = (cs[rho-1] - v) / (float)rho;
  float wpv = copysignf(fmaxf(aw - theta, 0.f), w);
  Wp[row*128 + j] = (l1 > v) ? wpv : w;
}

// Y = X @ Wp + U @ B  (concatenated K=256), 64 rows x 128 cols per block, 8x4 per thread.
// Double-buffered LDS; staging via global_load_lds (zero VGPR cost -> no spill, unlike r12).
// As is UNPADDED [64][32]: both A and W LDS destinations are wave-uniform-base + lane*16
// (lane l -> byte 1024*wv + 16*l), the layout global_load_lds requires. A-reads in compute
// are half-wave broadcasts (2 addrs/wave = free); Ws reads sweep all 32 banks conflict-free.
__global__ __launch_bounds__(256) void k_gemm(const float* __restrict__ X, const float* __restrict__ U,
                                              const float* __restrict__ Wp, const float* __restrict__ Bm,
                                              unsigned short* __restrict__ Ybf){
  __shared__ float As[2][64][32];         // 2 x 8 KB
  __shared__ float Ws[2][32][128];        // 2 x 16 KB
  int t  = threadIdx.x;
  int tc = t & 31, tr = t >> 5;           // tc: 4-col group (col=tc*4), tr: 8-row group
  int wv = t >> 6, lane = t & 63;
  int row0 = blockIdx.x * 64;

  // staging geometry (derived, wave-contiguous):
  int arow = 8*wv + (lane >> 3);          // 0..31 ; rows arow and arow+32
  int acol = (lane & 7) * 4;              // float offset in 32-float chunk
  int ga0r = row0 + arow;     if (ga0r >= NN) ga0r = NN-1;   // clamp OOB (results discarded)
  int ga1r = row0 + arow + 32; if (ga1r >= NN) ga1r = NN-1;
  int wrow = 2*wv + (lane >> 5);          // 0..7 ; rows wrow + 8*i
  int wcol = (lane & 31) * 4;

  float4 acc[8];
  #pragma unroll
  for (int m=0;m<8;++m) acc[m] = make_float4(0.f,0.f,0.f,0.f);

  #define STAGE(b, ci) { \
    const float* asrc_ = ((ci) < 4) ? X  : U; \
    const float* wsrc_ = ((ci) < 4) ? Wp : Bm; \
    int ko_ = ((ci) & 3) * 32; \
    gll16(asrc_ + (size_t)ga0r*128 + ko_ + acol, (char*)&As[b][0][0] + 1024*wv); \
    gll16(asrc_ + (size_t)ga1r*128 + ko_ + acol, (char*)&As[b][0][0] + 4096 + 1024*wv); \
    gll16(wsrc_ + (size_t)(ko_ + wrow     )*128 + wcol, (char*)&Ws[b][0][0] +     1024*wv); \
    gll16(wsrc_ + (size_t)(ko_ + wrow +  8)*128 + wcol, (char*)&Ws[b][0][0] + 4096 + 1024*wv); \
    gll16(wsrc_ + (size_t)(ko_ + wrow + 16)*128 + wcol, (char*)&Ws[b][0][0] + 8192 + 1024*wv); \
    gll16(wsrc_ + (size_t)(ko_ + wrow + 24)*128 + wcol, (char*)&Ws[b][0][0] + 12288 + 1024*wv); \
  }

  STAGE(0, 0);
  __syncthreads();                        // compiler drains vmcnt before s_barrier
  #pragma unroll 1
  for (int ci=0; ci<8; ++ci){
    int cur = ci & 1;
    if (ci < 7) STAGE(cur^1, ci+1);       // issue async loads; latency hides under FMA below
    #pragma unroll
    for (int k4=0;k4<8;++k4){
      float4 b0 = *(float4*)&Ws[cur][k4*4+0][tc*4];
      float4 b1 = *(float4*)&Ws[cur][k4*4+1][tc*4];
      float4 b2 = *(float4*)&Ws[cur][k4*4+2][tc*4];
      float4 b3 = *(float4*)&Ws[cur][k4*4+3][tc*4];
      #pragma unroll
      for (int m=0;m<8;++m){
        float4 a = *(float4*)&As[cur][tr*8+m][k4*4];
        FMA4(acc[m], a.x, b0); FMA4(acc[m], a.y, b1);
        FMA4(acc[m], a.z, b2); FMA4(acc[m], a.w, b3);
      }
    }
    __syncthreads();
  }
  #undef STAGE
  #pragma unroll
  for (int m=0;m<8;++m){
    int gr = row0 + tr*8 + m;
    if (gr < NN){
      ushort4 o;
      o.x = f2bf(acc[m].x); o.y = f2bf(acc[m].y); o.z = f2bf(acc[m].z); o.w = f2bf(acc[m].w);
      *(ushort4*)(Ybf + (size_t)gr*128 + tc*4) = o;
    }
  }
}

// out = relu(A @ Y_bf16), one wave per row; lane handles cols {2l, 2l+1} via one 4B gather/edge
__global__ __launch_bounds__(256) void k_spmm_relu(const int* __restrict__ rp, const float2* __restrict__ epk,
                                                   const unsigned int* __restrict__ Ybf2,  // N x 64 ushort2-words
                                                   float* __restrict__ out){
  int wv = threadIdx.x >> 6, lane = threadIdx.x & 63;
  int r = blockIdx.x*4 + wv;
  if (r >= NN) return;
  int e0 = rp[r], e1 = rp[r+1];
  float a0 = 0.f, a1 = 0.f;
  int e = e0;
  for (; e+2 <= e1; e += 2){
    float2 d0 = epk[e], d1 = epk[e+1];
    unsigned p0 = Ybf2[(size_t)__float_as_int(d0.y)*64 + lane];
    unsigned p1 = Ybf2[(size_t)__float_as_int(d1.y)*64 + lane];
    a0 = fmaf(d0.x, __uint_as_float(p0 << 16),         a0);
    a1 = fmaf(d0.x, __uint_as_float(p0 & 0xFFFF0000u), a1);
    a0 = fmaf(d1.x, __uint_as_float(p1 << 16),         a0);
    a1 = fmaf(d1.x, __uint_as_float(p1 & 0xFFFF0000u), a1);
  }
  if (e < e1){
    float2 d0 = epk[e];
    unsigned p0 = Ybf2[(size_t)__float_as_int(d0.y)*64 + lane];
    a0 = fmaf(d0.x, __uint_as_float(p0 << 16),         a0);
    a1 = fmaf(d0.x, __uint_as_float(p0 & 0xFFFF0000u), a1);
  }
  float2 o; o.x = fmaxf(a0, 0.f); o.y = fmaxf(a1, 0.f);
  *(float2*)(out + (size_t)r*128 + 2*lane) = o;
}

extern "C" void kernel_launch(void* const* d_in, const int* in_sizes, int n_in,
                              void* d_out, int out_size, void* d_ws, size_t ws_size,
                              hipStream_t stream) {
  const float* X  = (const float*)d_in[0];
  const float* U  = (const float*)d_in[1];
  const float* W  = (const float*)d_in[2];
  const float* Bm = (const float*)d_in[3];
  const float* ev = (const float*)d_in[4];
  const int*   ei = (const int*)d_in[5];
  const int* erow = ei;
  const int* ecol = ei + EE;

  char* ws = (char*)d_ws;
  int*            cnt  = (int*)           (ws + O_CNT);
  int*            rp   = (int*)           (ws + O_RP);
  int*            fill = (int*)           (ws + O_FILL);
  float2*         epk  = (float2*)        (ws + O_EPK);
  float*          ua   = (float*)         (ws + O_U0);
  float*          ub   = (float*)         (ws + O_U1);
  float*          n2   = (float*)         (ws + O_N2);
  float*          Wp   = (float*)         (ws + O_WP);
  unsigned short* Ybf  = (unsigned short*)(ws + O_Y);
  float*          out  = (float*)         d_out;
  // bsum/boff alias u0: used only during CSR build, before ua is first written (it=1)
  int*            bsum = (int*)           (ws + O_U0);
  int*            boff = (int*)           (ws + O_U0 + 1024);

  k_init   <<<196, 256, 0, stream>>>(cnt, n2);
  k_hist   <<<EE/256, 256, 0, stream>>>(erow, cnt);
  k_bsum   <<<196, 256, 0, stream>>>(cnt, bsum);
  k_bscan  <<<1, 256, 0, stream>>>(bsum, boff);
  k_scan3  <<<196, 256, 0, stream>>>(cnt, boff, rp, fill);
  k_scatter<<<EE/256, 256, 0, stream>>>(erow, ecol, ev, fill, epk);

  float* uav = ua; float* ubv = ub;
  for (int it = 0; it < NAPP; ++it){
    const float* n2prev = n2 + (it > 0 ? (it-1) : 0) * NSLOT*32;
    float*       n2cur  = n2 + it * NSLOT*32;
    k_spmv<<<782, 256, 0, stream>>>(rp, epk, uav, ubv, n2prev, n2cur, it == 0 ? 1 : 0);
    float* tmp = uav; uav = ubv; ubv = tmp;
  }

  k_proj     <<<128,   128, 0, stream>>>(W, n2 + (NAPP-1)*NSLOT*32, Wp);
  k_gemm     <<<782,   256, 0, stream>>>(X, U, Wp, Bm, Ybf);
  k_spmm_relu<<<12500, 256, 0, stream>>>(rp, epk, (const unsigned int*)Ybf, out);
}

// Round 14
// 323.065 us; speedup vs baseline: 1.1225x; 1.0873x over previous
//
#include <hip/hip_runtime.h>
#include <math.h>

#define NN 50000
#define EE 800000
#define NAPP 8             // A-applications; rho rel-err ~ 0.29^7 ~ 2e-4, output delta << threshold
#define NSLOT 8            // norm^2 partial slots per iteration, 1 cacheline apart

// ---- workspace byte offsets ----
static constexpr size_t O_CNT  = 0;         // N int32
static constexpr size_t O_RP   = 200192;    // (N+1) int32
static constexpr size_t O_FILL = 400640;    // N int32
static constexpr size_t O_EPK  = 600832;    // E * 8B packed {f32 val, i32 col} -> ends at 7000832
static constexpr size_t O_U0   = 7000832;   // N f32 (aliased: bsum/boff during CSR build)
static constexpr size_t O_U1   = 7201024;   // N f32
static constexpr size_t O_N2   = 7401216;   // NAPP * NSLOT*32 f32 (slot j at +j*128B)
static constexpr size_t O_BT   = 7414016;   // [Wp;B]^T bf16, MFMA-tiled, 128*256*2 = 65536 B
static constexpr size_t O_Y    = 7479552;   // N*128 bf16 (X@Wp + U@B), 12.8 MB

typedef __attribute__((ext_vector_type(8))) short bf16x8;
typedef __attribute__((ext_vector_type(4))) float f32x4;

__device__ __forceinline__ float slot_sum(const float* base){
  float s = 0.f;
  #pragma unroll
  for (int j = 0; j < NSLOT; ++j) s += base[j*32];
  return s;
}

__device__ __forceinline__ unsigned short f2bf(float x){   // RNE f32 -> bf16
  unsigned u = __float_as_uint(x);
  u = (u + 0x7FFFu + ((u >> 16) & 1u)) >> 16;
  return (unsigned short)u;
}
__device__ __forceinline__ unsigned pk2(float a, float b){
  return (unsigned)f2bf(a) | ((unsigned)f2bf(b) << 16);
}

// BT element index for (col j in 0..127, k in 0..255), fragment-tiled so a wave's
// 8-frag read for (n-tile, k-chunk) is one contiguous 1KB block:
// idx = ((n*8 + kc)*64 + (j&15)*4 + kg)*8 + (k&7),  n=j>>4, kc=k>>5, kg=(k&31)>>3
__device__ __forceinline__ size_t bt_idx(int j, int k){
  return (size_t)((((j >> 4)*8 + (k >> 5))*64 + (j & 15)*4 + ((k & 31) >> 3))*8 + (k & 7));
}

__global__ __launch_bounds__(256) void k_init(int* __restrict__ cnt, float* __restrict__ n2){
  int i = blockIdx.x*256 + threadIdx.x;
  if (i < NN) cnt[i] = 0;
  if (i < NAPP*NSLOT*32) n2[i] = 0.f;
}

__global__ __launch_bounds__(256) void k_hist(const int* __restrict__ erow, int* __restrict__ cnt){
  int e = blockIdx.x*256 + threadIdx.x;
  if (e < EE) atomicAdd(&cnt[erow[e]], 1);
}

// ---- hierarchical exclusive scan of cnt[] -> rp[], fill[] ----
__global__ __launch_bounds__(256) void k_bsum(const int* __restrict__ cnt, int* __restrict__ bsum){
  int i = blockIdx.x*256 + threadIdx.x;
  int v = (i < NN) ? cnt[i] : 0;
  for (int o=32;o>0;o>>=1) v += __shfl_down(v, o);
  __shared__ int red[4];
  int lane = threadIdx.x & 63, wv = threadIdx.x >> 6;
  if (lane == 0) red[wv] = v;
  __syncthreads();
  if (threadIdx.x == 0) bsum[blockIdx.x] = red[0]+red[1]+red[2]+red[3];
}

__global__ __launch_bounds__(256) void k_bscan(const int* __restrict__ bsum, int* __restrict__ boff){
  __shared__ int sd[256];
  int t = threadIdx.x;
  int v = (t < 196) ? bsum[t] : 0;
  sd[t] = v;
  __syncthreads();
  for (int off=1; off<256; off<<=1){
    int add = (t>=off) ? sd[t-off] : 0;
    __syncthreads();
    sd[t] += add;
    __syncthreads();
  }
  if (t < 196) boff[t] = sd[t] - v;   // exclusive block offset
}

__global__ __launch_bounds__(256) void k_scan3(const int* __restrict__ cnt, const int* __restrict__ boff,
                                               int* __restrict__ rp, int* __restrict__ fill){
  __shared__ int sd[256];
  int t = threadIdx.x, i = blockIdx.x*256 + t;
  int c = (i < NN) ? cnt[i] : 0;
  sd[t] = c;
  __syncthreads();
  for (int off=1; off<256; off<<=1){
    int add = (t>=off) ? sd[t-off] : 0;
    __syncthreads();
    sd[t] += add;
    __syncthreads();
  }
  int excl = sd[t] - c + boff[blockIdx.x];
  if (i < NN){ fill[i] = excl; rp[i+1] = excl + c; }
  if (i == 0) rp[0] = 0;
}

__global__ __launch_bounds__(256) void k_scatter(const int* __restrict__ erow, const int* __restrict__ ecol,
                                                 const float* __restrict__ ev, int* __restrict__ fill,
                                                 float2* __restrict__ epk){
  int e = blockIdx.x*256 + threadIdx.x;
  if (e < EE){
    int r = erow[e];
    int p = atomicAdd(&fill[r], 1);
    epk[p] = make_float2(ev[e], __int_as_float(ecol[e]));
  }
}

// One power-iteration step, 4 lanes per row. Scale for this step comes from the
// PREVIOUS launch's n2 slots (kernel boundary = grid barrier). Partials for this
// step go to 8 cacheline-spread slots — no same-line contention, no finalize.
__global__ __launch_bounds__(256) void k_spmv(const int* __restrict__ rp, const float2* __restrict__ epk,
                                              const float* __restrict__ uin, float* __restrict__ uout,
                                              const float* __restrict__ n2prev, float* __restrict__ n2cur,
                                              int first_flag){
  int tid = blockIdx.x*256 + threadIdx.x;
  int r = tid >> 2, q = tid & 3;
  float s = first_flag ? 0.004472135955f                      // 1/sqrt(50000): v0 = ones/sqrt(N)
                       : 1.0f / (sqrtf(slot_sum(n2prev)) + 1e-12f);
  float acc = 0.f;
  if (r < NN){
    int e0 = rp[r], e1 = rp[r+1];
    if (first_flag){
      for (int e = e0 + q; e < e1; e += 4) acc += epk[e].x;   // uin == all-ones (folded)
    } else {
      for (int e = e0 + q; e < e1; e += 4){
        float2 ed = epk[e];
        acc = fmaf(ed.x, uin[__float_as_int(ed.y)], acc);
      }
    }
  }
  acc += __shfl_xor(acc, 1);
  acc += __shfl_xor(acc, 2);
  acc *= s;
  float p2 = 0.f;
  if (r < NN && q == 0){ uout[r] = acc; p2 = acc*acc; }
  for (int o=32;o>0;o>>=1) p2 += __shfl_down(p2, o);
  __shared__ float red[4];
  int lane = threadIdx.x & 63, wv = threadIdx.x >> 6;
  if (lane == 0) red[wv] = p2;
  __syncthreads();
  if (threadIdx.x == 0)
    atomicAdd(&n2cur[(blockIdx.x & (NSLOT-1)) * 32], red[0]+red[1]+red[2]+red[3]);
}

// Row-wise L1-ball projection of W; emits bf16 TRANSPOSED fragment-tiled BT[:, 0..127].
// blockIdx.x = k (the Wp row index = K index in A@Wp), thread j = output column.
__global__ __launch_bounds__(128) void k_proj(const float* __restrict__ W, const float* __restrict__ n2last,
                                              unsigned short* __restrict__ BT){
  __shared__ float sa[128];
  __shared__ float cs[128];
  __shared__ int wcnt[2];
  int row = blockIdx.x, j = threadIdx.x;
  float w  = W[row*128 + j];
  float aw = fabsf(w);
  float v  = 0.99f / (sqrtf(slot_sum(n2last)) + 1e-5f);       // kappa/(rho+eps)
  sa[j] = aw;
  __syncthreads();
  // bitonic sort ascending
  for (int k=2; k<=128; k<<=1){
    for (int jj=k>>1; jj>0; jj>>=1){
      int ix = j ^ jj;
      if (ix > j){
        float x = sa[j], y = sa[ix];
        bool up = ((j & k) == 0);
        if ((x > y) == up){ sa[j] = y; sa[ix] = x; }
      }
      __syncthreads();
    }
  }
  float d = sa[127 - j];                  // descending view
  cs[j] = d;
  __syncthreads();
  for (int off=1; off<128; off<<=1){      // inclusive scan
    float add = (j>=off) ? cs[j-off] : 0.f;
    __syncthreads();
    cs[j] += add;
    __syncthreads();
  }
  float l1 = cs[127];
  int flag = (d * (float)(j+1) > cs[j] - v) ? 1 : 0;
  unsigned long long bal = __ballot(flag);
  if ((j & 63) == 0) wcnt[j>>6] = __popcll(bal);
  __syncthreads();
  int rho = wcnt[0] + wcnt[1];            // >=1 always (v>0)
  float theta = (cs[rho-1] - v) / (float)rho;
  float wpv = copysignf(fmaxf(aw - theta, 0.f), w);
  float res = (l1 > v) ? wpv : w;
  BT[bt_idx(j, row)] = f2bf(res);
}

// B matrix -> bf16 transposed fragment-tiled BT[:, 128..255]. blockIdx.x = B row (k-128).
__global__ __launch_bounds__(128) void k_cvtB(const float* __restrict__ Bm, unsigned short* __restrict__ BT){
  int bk = blockIdx.x, j = threadIdx.x;
  BT[bt_idx(j, 128 + bk)] = f2bf(Bm[bk*128 + j]);
}

// Y = [X|U] @ [Wp;B] in bf16 MFMA (f32 accum). 64 rows/block, 4 waves; each wave owns a
// 16-row strip x 128 cols = 8 mfma 16x16x32 tiles x 8 K-chunks. A reg-staged with f32->bf16
// cvt into 8KB dbuf LDS (1 ds_write_b128 + 1 ds_read_b128 per wave per chunk); B-frags read
// straight from L2 (BT is 64KB, fragment-tiled -> each (tile,chunk) read = contiguous 1KB).
// Frag maps: A lane l -> row l&15, k=8*(l>>4)+e ; B lane l -> col l&15, k=8*(l>>4)+e ;
// D lane l, reg r -> row 4*(l>>4)+r, col l&15  [m89-verified].
__global__ __launch_bounds__(256) void k_gemm(const float* __restrict__ X, const float* __restrict__ U,
                                              const unsigned short* __restrict__ BT,
                                              unsigned short* __restrict__ Ybf){
  __shared__ uint4 As[2][256];            // 2 x 4KB : [64 rows][32 k] bf16
  int t = threadIdx.x;
  int w = t >> 6, l = t & 63;
  int l15 = l & 15, l4 = l >> 4;
  int row0 = blockIdx.x * 64;
  int srow = t >> 2, sk = (t & 3) * 8;    // staging: row, k-offset (8 floats -> 8 bf16)
  int sgr = row0 + srow; if (sgr >= NN) sgr = NN - 1;   // clamp; results discarded at C-write

  f32x4 acc[8];
  #pragma unroll
  for (int n=0;n<8;++n) acc[n] = (f32x4){0.f,0.f,0.f,0.f};

  float4 pa0, pa1;
  pa0 = *(const float4*)(X + (size_t)sgr*128 + sk);
  pa1 = *(const float4*)(X + (size_t)sgr*128 + sk + 4);
  {
    uint4 pk; pk.x = pk2(pa0.x, pa0.y); pk.y = pk2(pa0.z, pa0.w);
    pk.z = pk2(pa1.x, pa1.y); pk.w = pk2(pa1.z, pa1.w);
    As[0][t] = pk;
  }
  __syncthreads();

  #pragma unroll 1
  for (int ci=0; ci<8; ++ci){
    int cur = ci & 1;
    if (ci < 7){                          // prefetch next chunk's A (8 VGPR; latency hides under MFMA)
      const float* asrc = (ci+1 < 4) ? X : U;
      int ko = ((ci+1) & 3) * 32;
      pa0 = *(const float4*)(asrc + (size_t)sgr*128 + ko + sk);
      pa1 = *(const float4*)(asrc + (size_t)sgr*128 + ko + sk + 4);
    }
    bf16x8 a = *(const bf16x8*)&As[cur][(w*16 + l15)*4 + l4];
    bf16x8 b[8];
    #pragma unroll
    for (int n=0;n<8;++n)
      b[n] = *(const bf16x8*)(BT + (size_t)((n*8 + ci)*512 + l15*32 + l4*8));
    #pragma unroll
    for (int n=0;n<8;++n)
      acc[n] = __builtin_amdgcn_mfma_f32_16x16x32_bf16(a, b[n], acc[n], 0, 0, 0);
    if (ci < 7){
      uint4 pk; pk.x = pk2(pa0.x, pa0.y); pk.y = pk2(pa0.z, pa0.w);
      pk.z = pk2(pa1.x, pa1.y); pk.w = pk2(pa1.z, pa1.w);
      As[cur^1][t] = pk;
    }
    __syncthreads();
  }

  #pragma unroll
  for (int n=0;n<8;++n){
    #pragma unroll
    for (int r=0;r<4;++r){
      int gr = row0 + w*16 + l4*4 + r;
      if (gr < NN) Ybf[(size_t)gr*128 + n*16 + l15] = f2bf(acc[n][r]);
    }
  }
}

// out = relu(A @ Y_bf16), one wave per row; lane handles cols {2l, 2l+1} via one 4B gather/edge
__global__ __launch_bounds__(256) void k_spmm_relu(const int* __restrict__ rp, const float2* __restrict__ epk,
                                                   const unsigned int* __restrict__ Ybf2,  // N x 64 ushort2-words
                                                   float* __restrict__ out){
  int wv = threadIdx.x >> 6, lane = threadIdx.x & 63;
  int r = blockIdx.x*4 + wv;
  if (r >= NN) return;
  int e0 = rp[r], e1 = rp[r+1];
  float a0 = 0.f, a1 = 0.f;
  int e = e0;
  for (; e+2 <= e1; e += 2){
    float2 d0 = epk[e], d1 = epk[e+1];
    unsigned p0 = Ybf2[(size_t)__float_as_int(d0.y)*64 + lane];
    unsigned p1 = Ybf2[(size_t)__float_as_int(d1.y)*64 + lane];
    a0 = fmaf(d0.x, __uint_as_float(p0 << 16),         a0);
    a1 = fmaf(d0.x, __uint_as_float(p0 & 0xFFFF0000u), a1);
    a0 = fmaf(d1.x, __uint_as_float(p1 << 16),         a0);
    a1 = fmaf(d1.x, __uint_as_float(p1 & 0xFFFF0000u), a1);
  }
  if (e < e1){
    float2 d0 = epk[e];
    unsigned p0 = Ybf2[(size_t)__float_as_int(d0.y)*64 + lane];
    a0 = fmaf(d0.x, __uint_as_float(p0 << 16),         a0);
    a1 = fmaf(d0.x, __uint_as_float(p0 & 0xFFFF0000u), a1);
  }
  float2 o; o.x = fmaxf(a0, 0.f); o.y = fmaxf(a1, 0.f);
  *(float2*)(out + (size_t)r*128 + 2*lane) = o;
}

extern "C" void kernel_launch(void* const* d_in, const int* in_sizes, int n_in,
                              void* d_out, int out_size, void* d_ws, size_t ws_size,
                              hipStream_t stream) {
  const float* X  = (const float*)d_in[0];
  const float* U  = (const float*)d_in[1];
  const float* W  = (const float*)d_in[2];
  const float* Bm = (const float*)d_in[3];
  const float* ev = (const float*)d_in[4];
  const int*   ei = (const int*)d_in[5];
  const int* erow = ei;
  const int* ecol = ei + EE;

  char* ws = (char*)d_ws;
  int*            cnt  = (int*)           (ws + O_CNT);
  int*            rp   = (int*)           (ws + O_RP);
  int*            fill = (int*)           (ws + O_FILL);
  float2*         epk  = (float2*)        (ws + O_EPK);
  float*          ua   = (float*)         (ws + O_U0);
  float*          ub   = (float*)         (ws + O_U1);
  float*          n2   = (float*)         (ws + O_N2);
  unsigned short* BT   = (unsigned short*)(ws + O_BT);
  unsigned short* Ybf  = (unsigned short*)(ws + O_Y);
  float*          out  = (float*)         d_out;
  // bsum/boff alias u0: used only during CSR build, before ua is first written (it=1)
  int*            bsum = (int*)           (ws + O_U0);
  int*            boff = (int*)           (ws + O_U0 + 1024);

  k_init   <<<196, 256, 0, stream>>>(cnt, n2);
  k_hist   <<<EE/256, 256, 0, stream>>>(erow, cnt);
  k_bsum   <<<196, 256, 0, stream>>>(cnt, bsum);
  k_bscan  <<<1, 256, 0, stream>>>(bsum, boff);
  k_scan3  <<<196, 256, 0, stream>>>(cnt, boff, rp, fill);
  k_scatter<<<EE/256, 256, 0, stream>>>(erow, ecol, ev, fill, epk);
  k_cvtB   <<<128, 128, 0, stream>>>(Bm, BT);          // independent of spmv chain

  float* uav = ua; float* ubv = ub;
  for (int it = 0; it < NAPP; ++it){
    const float* n2prev = n2 + (it > 0 ? (it-1) : 0) * NSLOT*32;
    float*       n2cur  = n2 + it * NSLOT*32;
    k_spmv<<<782, 256, 0, stream>>>(rp, epk, uav, ubv, n2prev, n2cur, it == 0 ? 1 : 0);
    float* tmp = uav; uav = ubv; ubv = tmp;
  }

  k_proj     <<<128,   128, 0, stream>>>(W, n2 + (NAPP-1)*NSLOT*32, BT);
  k_gemm     <<<782,   256, 0, stream>>>(X, U, BT, Ybf);
  k_spmm_relu<<<12500, 256, 0, stream>>>(rp, epk, (const unsigned int*)Ybf, out);
}